// Round 8
// baseline (211.474 us; speedup 1.0000x reference)
//
#include <hip/hip_runtime.h>
#include <math.h>

#define LHIST 50

typedef __attribute__((ext_vector_type(8))) short bf16x8;
typedef __attribute__((ext_vector_type(4))) float f32x4;

__device__ __forceinline__ unsigned short f2bf(float f) {
    union { float f; unsigned u; } v; v.f = f;
    unsigned r = v.u + 0x7fff + ((v.u >> 16) & 1);   // RNE
    return (unsigned short)(r >> 16);
}
__device__ __forceinline__ float bf2f(unsigned short h) {
    union { unsigned u; float f; } v; v.u = ((unsigned)h) << 16;
    return v.f;
}
__device__ __forceinline__ unsigned packbf2(float lo, float hi) {
    return (unsigned)f2bf(lo) | ((unsigned)f2bf(hi) << 16);
}

// ws float offsets:
//  Awt    [80][64] fp32                   @ 0         (5120)
//  Bmfb   frag bf16 [nt5][ks2][lane][8]   @ 5120      (2560 f)
//  W4fb   frag bf16 [nt5][ks2][lane][8]   @ 7680      (2560 f)
//  W1f    frag bf16 [nt16][ks5][lane][8]  @ 10240     (20480 f)
//  W2f    frag bf16 [nt8][ks8][lane][8]   @ 30720     (16384 f)
//  itemb  bf16 [NI*32]                    @ 47104     (NI*16 f)
//  catb   bf16 [NC*32]                    @ 47104+NI*16
//  cfrag  bf16 [B/16][ks5][lane][8]       after catb  (combined, MFMA A-frag layout)

__global__ void prep_kernel(const float* __restrict__ aw1,
                            const float* __restrict__ mw1,
                            const float* __restrict__ mw2,
                            const float* __restrict__ item_table,
                            const float* __restrict__ cat_table,
                            int itemN, int catN,
                            float* __restrict__ Awt,
                            unsigned short* __restrict__ Bmfb,
                            unsigned short* __restrict__ W4fb,
                            unsigned short* __restrict__ W1f,
                            unsigned short* __restrict__ W2f,
                            unsigned short* __restrict__ itemb,
                            unsigned short* __restrict__ catb) {
    int i = blockIdx.x * 256 + threadIdx.x;
    int i8 = i * 8;
    if (i8 + 7 < itemN) {
        float4 a = *(const float4*)&item_table[i8];
        float4 b = *(const float4*)&item_table[i8 + 4];
        uint4 r;
        r.x = packbf2(a.x, a.y); r.y = packbf2(a.z, a.w);
        r.z = packbf2(b.x, b.y); r.w = packbf2(b.z, b.w);
        *(uint4*)&itemb[i8] = r;
    }
    if (i8 + 7 < catN) {
        float4 a = *(const float4*)&cat_table[i8];
        float4 b = *(const float4*)&cat_table[i8 + 4];
        uint4 r;
        r.x = packbf2(a.x, a.y); r.y = packbf2(a.z, a.w);
        r.z = packbf2(b.x, b.y); r.w = packbf2(b.z, b.w);
        *(uint4*)&catb[i8] = r;
    }
    if (i < 5120) {
        int j = i >> 6, k = i & 63;
        Awt[i] = aw1[k * 80 + j] + aw1[(128 + k) * 80 + j];     // (W1+W3)^T
        int kk = i / 80, n = i - kk * 80;
        int nt = n >> 4, colw = n & 15, ks = kk >> 5, r = kk & 31, qd = r >> 3, off = r & 7;
        int d = ((nt * 2 + ks) * 64 + qd * 16 + colw) * 8 + off;
        Bmfb[d] = f2bf(aw1[(64 + kk) * 80 + n] - aw1[(128 + kk) * 80 + n]);  // W2-W3
        W4fb[d] = f2bf(aw1[(192 + kk) * 80 + n]);
    }
    if (i < 40960) {
        int kk = i >> 8, n = i & 255;
        int nt = n >> 4, colw = n & 15, ks = kk >> 5, r = kk & 31, qd = r >> 3, off = r & 7;
        W1f[((nt * 5 + ks) * 64 + qd * 16 + colw) * 8 + off] = f2bf(mw1[i]);
    }
    if (i < 32768) {
        int kk = i >> 7, n = i & 127;
        int nt = n >> 4, colw = n & 15, ks = kk >> 5, r = kk & 31, qd = r >> 3, off = r & 7;
        W2f[((nt * 8 + ks) * 64 + qd * 16 + colw) * 8 + off] = f2bf(mw2[i]);
    }
}

// ---------- attention: 4 batches/block (1 per wave), K=64, per-batch B' in LDS ----------
__global__ void __launch_bounds__(256, 4) attn_kernel(
    const int* __restrict__ cid, const int* __restrict__ cg,
    const int* __restrict__ cc,  const int* __restrict__ hg,
    const int* __restrict__ hc,
    const float* __restrict__ user_table, const float* __restrict__ item_table,
    const float* __restrict__ cat_table,
    const float* __restrict__ ab1, const float* __restrict__ aw2,
    const float* __restrict__ Awt, const unsigned short* __restrict__ Bmfb,
    const unsigned short* __restrict__ W4fb,
    const unsigned short* __restrict__ itemb, const unsigned short* __restrict__ catb,
    unsigned short* __restrict__ cfrag)
{
    __shared__ __align__(16) unsigned short sh_Bq[4][5120];   // [b][nt5][ks2][lane][8]
    __shared__ __align__(16) float sh_q[4][64];
    __shared__ float sh_bias[4][80];
    __shared__ float sh_sc[4][64];
    __shared__ float sh_aw2[80];
    __shared__ __align__(16) float sh_att[4][64];

    const int t = threadIdx.x;
    const int b0 = blockIdx.x * 4;
    const int wv = t >> 6;
    const int lane = t & 63;
    const int quad = lane >> 4;
    const int col = lane & 15;
    const int b = b0 + wv;

    // ---- P0: per-wave history indices + issue ALL h-gathers immediately ----
    int il[4], ic[4];
    #pragma unroll
    for (int mt = 0; mt < 4; ++mt) {
        int l = mt * 16 + col;
        int lc = (l < LHIST) ? l : 0;
        il[mt] = hg[b * LHIST + lc];
        ic[mt] = hc[b * LHIST + lc];
    }
    uint4 vi[4], vc[4];
    #pragma unroll
    for (int mt = 0; mt < 4; ++mt) {
        vi[mt] = *(const uint4*)&itemb[(size_t)il[mt] * 32 + quad * 8];
        vc[mt] = *(const uint4*)&catb[(size_t)ic[mt] * 32 + quad * 8];
    }
    // q (fp32 tables) + aw2
    {
        float v = (lane < 32) ? item_table[(size_t)cg[b] * 32 + lane]
                              : cat_table[(size_t)cc[b] * 32 + (lane - 32)];
        sh_q[wv][lane] = v;
    }
    if (t < 80) sh_aw2[t] = aw2[t];
    __syncthreads();

    // ---- P1: B' = Bm + diag(q).W4 per batch, built by all 256 threads ----
    // 4 batches x 5120 elems = 20480 elems = 2560 slots of 8 = 10 iterations
    #pragma unroll
    for (int it = 0; it < 10; ++it) {
        int i = it * 256 + t;                 // 0..2559
        int bb = i / 640;                     // 640 slots per batch
        int j = (i - bb * 640) * 8;           // elem offset in [0,5120)
        int lane8 = (j >> 3) & 63, ks = (j >> 9) & 1;
        int kk = ks * 32 + (lane8 >> 4) * 8;
        uint4 bm4 = *(const uint4*)&Bmfb[j];
        uint4 w44 = *(const uint4*)&W4fb[j];
        float4 qa = *(const float4*)&sh_q[bb][kk];
        float4 qb = *(const float4*)&sh_q[bb][kk + 4];
        unsigned bmw[4] = {bm4.x, bm4.y, bm4.z, bm4.w};
        unsigned w4w[4] = {w44.x, w44.y, w44.z, w44.w};
        float qv[8] = {qa.x, qa.y, qa.z, qa.w, qb.x, qb.y, qb.z, qb.w};
        uint4 res;
        unsigned* rp = (unsigned*)&res;
        #pragma unroll
        for (int d = 0; d < 4; ++d) {
            float lo = bf2f((unsigned short)(bmw[d] & 0xffff)) + qv[2 * d]     * bf2f((unsigned short)(w4w[d] & 0xffff));
            float hi = bf2f((unsigned short)(bmw[d] >> 16))    + qv[2 * d + 1] * bf2f((unsigned short)(w4w[d] >> 16));
            rp[d] = packbf2(lo, hi);
        }
        *(uint4*)&sh_Bq[bb][j] = res;
    }
    // bias[b][j] = ab1[j] + q.(W1+W3)[:,j]  (fp32 exact)
    for (int s = t; s < 320; s += 256) {
        int bi = s / 80, j = s - bi * 80;
        float acc = ab1[j];
        const float4* aw = (const float4*)&Awt[j * 64];
        #pragma unroll
        for (int k4 = 0; k4 < 16; ++k4) {
            float4 a = aw[k4];
            float4 q = *(const float4*)&sh_q[bi][k4 * 4];
            acc += a.x * q.x + a.y * q.y + a.z * q.z + a.w * q.w;
        }
        sh_bias[bi][j] = acc;
    }
    __syncthreads();

    float bias_v[5], a2_v[5];
    #pragma unroll
    for (int nt = 0; nt < 5; ++nt) {
        bias_v[nt] = sh_bias[wv][nt * 16 + col];
        a2_v[nt]   = sh_aw2[nt * 16 + col];
    }

    // ---- P2: MFMA u = h[64 rows x K64] @ B'[64x80], two mt-pairs ----
    #pragma unroll
    for (int p = 0; p < 2; ++p) {
        f32x4 acc[2][5];
        #pragma unroll
        for (int mi = 0; mi < 2; ++mi)
            #pragma unroll
            for (int nt = 0; nt < 5; ++nt) acc[mi][nt] = (f32x4){0.f,0.f,0.f,0.f};
        bf16x8 a0i = *(bf16x8*)&vi[p * 2];
        bf16x8 a0c = *(bf16x8*)&vc[p * 2];
        bf16x8 a1i = *(bf16x8*)&vi[p * 2 + 1];
        bf16x8 a1c = *(bf16x8*)&vc[p * 2 + 1];
        #pragma unroll
        for (int nt = 0; nt < 5; ++nt) {
            bf16x8 b0 = *(const bf16x8*)&sh_Bq[wv][((nt * 2 + 0) * 64 + lane) * 8];
            acc[0][nt] = __builtin_amdgcn_mfma_f32_16x16x32_bf16(a0i, b0, acc[0][nt], 0, 0, 0);
            acc[1][nt] = __builtin_amdgcn_mfma_f32_16x16x32_bf16(a1i, b0, acc[1][nt], 0, 0, 0);
            bf16x8 b1 = *(const bf16x8*)&sh_Bq[wv][((nt * 2 + 1) * 64 + lane) * 8];
            acc[0][nt] = __builtin_amdgcn_mfma_f32_16x16x32_bf16(a0c, b1, acc[0][nt], 0, 0, 0);
            acc[1][nt] = __builtin_amdgcn_mfma_f32_16x16x32_bf16(a1c, b1, acc[1][nt], 0, 0, 0);
        }
        // epilogue: scores = relu(u+bias).aw2, reduce over 16 col lanes
        #pragma unroll
        for (int mi = 0; mi < 2; ++mi) {
            int mt = p * 2 + mi;
            #pragma unroll
            for (int i = 0; i < 4; ++i) {
                float pp = 0.f;
                #pragma unroll
                for (int nt = 0; nt < 5; ++nt) {
                    float u = acc[mi][nt][i] + bias_v[nt];
                    pp += fmaxf(u, 0.f) * a2_v[nt];
                }
                pp += __shfl_xor(pp, 1);
                pp += __shfl_xor(pp, 2);
                pp += __shfl_xor(pp, 4);
                pp += __shfl_xor(pp, 8);
                if (col == 0) sh_sc[wv][mt * 16 + quad * 4 + i] = pp;
            }
        }
    }

    // ---- softmax (wave-local) ----
    float sc = -INFINITY;
    if (lane < LHIST) {
        sc = sh_sc[wv][lane];
        if (hg[b * LHIST + lane] == 0) sc = -1e9f;
    }
    float m = sc;
    #pragma unroll
    for (int off = 32; off > 0; off >>= 1) m = fmaxf(m, __shfl_xor(m, off));
    float e = (lane < LHIST) ? __expf(sc - m) : 0.f;
    float ssum = e;
    #pragma unroll
    for (int off = 32; off > 0; off >>= 1) ssum += __shfl_xor(ssum, off);
    float w = e / ssum;    // 0 for lane >= LHIST

    // ---- att from live h-frags: wl broadcast + per-lane partials + col-reduce ----
    {
        float wl[4];
        wl[0] = __shfl(w, col);
        wl[1] = __shfl(w, 16 + col);
        wl[2] = __shfl(w, 32 + col);
        wl[3] = __shfl(w, 48 + col);
        float at0[8], at1[8];
        #pragma unroll
        for (int j = 0; j < 8; ++j) { at0[j] = 0.f; at1[j] = 0.f; }
        #pragma unroll
        for (int mt = 0; mt < 4; ++mt) {
            union { uint4 u; unsigned short s[8]; } hi, hcv;
            hi.u = vi[mt]; hcv.u = vc[mt];
            #pragma unroll
            for (int j = 0; j < 8; ++j) {
                at0[j] += wl[mt] * bf2f(hi.s[j]);
                at1[j] += wl[mt] * bf2f(hcv.s[j]);
            }
        }
        #pragma unroll
        for (int off = 1; off < 16; off <<= 1)
            #pragma unroll
            for (int j = 0; j < 8; ++j) {
                at0[j] += __shfl_xor(at0[j], off);
                at1[j] += __shfl_xor(at1[j], off);
            }
        if (col == 0) {   // lanes 0,16,32,48: quad holds d = quad*8+j (item), 32+quad*8+j (cat)
            *(float4*)&sh_att[wv][quad * 8]     = make_float4(at0[0], at0[1], at0[2], at0[3]);
            *(float4*)&sh_att[wv][quad * 8 + 4] = make_float4(at0[4], at0[5], at0[6], at0[7]);
            *(float4*)&sh_att[wv][32 + quad * 8]     = make_float4(at1[0], at1[1], at1[2], at1[3]);
            *(float4*)&sh_att[wv][32 + quad * 8 + 4] = make_float4(at1[4], at1[5], at1[6], at1[7]);
        }
    }

    // ---- write combined directly in MFMA A-frag layout (bf16) ----
    {
        int g = b >> 4, colm = b & 15;
        unsigned short* base = cfrag + (size_t)g * 2560;
        if (lane < 8) {                       // att chunks: k = 96 + lane*8
            float4 aa = *(const float4*)&sh_att[wv][lane * 8];
            float4 ab = *(const float4*)&sh_att[wv][lane * 8 + 4];
            int k0 = 96 + lane * 8;
            int ks = k0 >> 5, qd = (k0 >> 3) & 3;
            uint4 r;
            r.x = packbf2(aa.x, aa.y); r.y = packbf2(aa.z, aa.w);
            r.z = packbf2(ab.x, ab.y); r.w = packbf2(ab.z, ab.w);
            *(uint4*)(base + ((ks * 64) + qd * 16 + colm) * 8) = r;
        } else if (lane < 16) {               // q chunks: k = 32 + (lane-8)*8
            int cq = lane - 8;
            int k0 = 32 + cq * 8;
            int ks = k0 >> 5, qd = (k0 >> 3) & 3;
            float4 qa = *(const float4*)&sh_q[wv][cq * 8];
            float4 qb = *(const float4*)&sh_q[wv][cq * 8 + 4];
            uint4 r;
            r.x = packbf2(qa.x, qa.y); r.y = packbf2(qa.z, qa.w);
            r.z = packbf2(qb.x, qb.y); r.w = packbf2(qb.z, qb.w);
            *(uint4*)(base + ((ks * 64) + qd * 16 + colm) * 8) = r;
        } else if (lane < 20) {               // user chunks: k = (lane-16)*8
            int cu = lane - 16;
            int uidx = cid[b];
            float4 ua = *(const float4*)&user_table[(size_t)uidx * 32 + cu * 8];
            float4 ub = *(const float4*)&user_table[(size_t)uidx * 32 + cu * 8 + 4];
            uint4 r;
            r.x = packbf2(ua.x, ua.y); r.y = packbf2(ua.z, ua.w);
            r.z = packbf2(ub.x, ub.y); r.w = packbf2(ub.z, ub.w);
            *(uint4*)(base + (cu * 16 + colm) * 8) = r;
        }
    }
}

// ---------- MLP: MFMA, 16 batches (1 m-tile) per 256-thread block ----------
__global__ void __launch_bounds__(256, 4) mlp_kernel(
    const unsigned short* __restrict__ cfrag,
    const unsigned short* __restrict__ W1f, const unsigned short* __restrict__ W2f,
    const float* __restrict__ mb1, const float* __restrict__ mb2,
    const float* __restrict__ mw3, const float* __restrict__ mb3,
    float* __restrict__ out)
{
    __shared__ __align__(16) unsigned short shA2[4096];   // [ks8][lane][8]
    __shared__ float sh_part[4][16];

    const int t = threadIdx.x;
    const int g = blockIdx.x;
    const int wv = t >> 6;
    const int lane = t & 63;
    const int quad = lane >> 4;
    const int col = lane & 15;
    const unsigned short* abase = cfrag + (size_t)g * 2560;

    f32x4 acc1[4];
    #pragma unroll
    for (int j = 0; j < 4; ++j) acc1[j] = (f32x4){0.f, 0.f, 0.f, 0.f};
    #pragma unroll
    for (int ks = 0; ks < 5; ++ks) {
        bf16x8 a = *(const bf16x8*)&abase[(ks * 64 + lane) * 8];
        #pragma unroll
        for (int j = 0; j < 4; ++j) {
            bf16x8 bw = *(const bf16x8*)&W1f[(((wv * 4 + j) * 5 + ks) * 64 + lane) * 8];
            acc1[j] = __builtin_amdgcn_mfma_f32_16x16x32_bf16(a, bw, acc1[j], 0, 0, 0);
        }
    }
    #pragma unroll
    for (int j = 0; j < 4; ++j) {
        int n = (wv * 4 + j) * 16 + col;
        float bj = mb1[n];
        int ks2 = n >> 5, qd2 = (n >> 3) & 3, off2 = n & 7;
        #pragma unroll
        for (int i = 0; i < 4; ++i) {
            float z = fmaxf(acc1[j][i] + bj, 0.f);
            shA2[(ks2 * 64 + qd2 * 16 + quad * 4 + i) * 8 + off2] = f2bf(z);
        }
    }
    __syncthreads();

    f32x4 acc2[2];
    #pragma unroll
    for (int jj = 0; jj < 2; ++jj) acc2[jj] = (f32x4){0.f, 0.f, 0.f, 0.f};
    #pragma unroll
    for (int ks = 0; ks < 8; ++ks) {
        bf16x8 a = *(const bf16x8*)&shA2[(ks * 64 + lane) * 8];
        #pragma unroll
        for (int jj = 0; jj < 2; ++jj) {
            bf16x8 bw = *(const bf16x8*)&W2f[(((wv * 2 + jj) * 8 + ks) * 64 + lane) * 8];
            acc2[jj] = __builtin_amdgcn_mfma_f32_16x16x32_bf16(a, bw, acc2[jj], 0, 0, 0);
        }
    }
    #pragma unroll
    for (int i = 0; i < 4; ++i) {
        float p = 0.f;
        #pragma unroll
        for (int jj = 0; jj < 2; ++jj) {
            int n = (wv * 2 + jj) * 16 + col;
            float z = fmaxf(acc2[jj][i] + mb2[n], 0.f);
            p += z * mw3[n];
        }
        p += __shfl_xor(p, 1);
        p += __shfl_xor(p, 2);
        p += __shfl_xor(p, 4);
        p += __shfl_xor(p, 8);
        if (col == 0) sh_part[wv][quad * 4 + i] = p;
    }
    __syncthreads();
    if (t < 16)
        out[g * 16 + t] = sh_part[0][t] + sh_part[1][t] + sh_part[2][t] + sh_part[3][t] + mb3[0];
}

extern "C" void kernel_launch(void* const* d_in, const int* in_sizes, int n_in,
                              void* d_out, int out_size, void* d_ws, size_t ws_size,
                              hipStream_t stream) {
    const int*   cid = (const int*)d_in[0];
    const int*   cg  = (const int*)d_in[1];
    const int*   cc  = (const int*)d_in[2];
    const int*   hg  = (const int*)d_in[3];
    const int*   hc  = (const int*)d_in[4];
    const float* user_table = (const float*)d_in[5];
    const float* item_table = (const float*)d_in[6];
    const float* cat_table  = (const float*)d_in[7];
    const float* aw1 = (const float*)d_in[8];
    const float* ab1 = (const float*)d_in[9];
    const float* aw2 = (const float*)d_in[10];
    const float* mw1 = (const float*)d_in[12];
    const float* mb1 = (const float*)d_in[13];
    const float* mw2 = (const float*)d_in[14];
    const float* mb2 = (const float*)d_in[15];
    const float* mw3 = (const float*)d_in[16];
    const float* mb3 = (const float*)d_in[17];
    float* out = (float*)d_out;

    const int B = in_sizes[0];                    // 16384
    const int itemN = in_sizes[6];                // NI*32
    const int catN  = in_sizes[7];                // NC*32
    float* ws = (float*)d_ws;
    float* Awt = ws;
    unsigned short* Bmfb = (unsigned short*)(ws + 5120);
    unsigned short* W4fb = (unsigned short*)(ws + 7680);
    unsigned short* W1f  = (unsigned short*)(ws + 10240);
    unsigned short* W2f  = (unsigned short*)(ws + 30720);
    unsigned short* itemb = (unsigned short*)(ws + 47104);
    unsigned short* catb  = itemb + itemN;
    unsigned short* cfrag = (unsigned short*)(ws + 47104 + (itemN + catN + 1) / 2);

    int n8 = (itemN + 7) / 8;
    int prep_grid = (n8 + 255) / 256;
    if (prep_grid < 160) prep_grid = 160;
    prep_kernel<<<prep_grid, 256, 0, stream>>>(aw1, mw1, mw2, item_table, cat_table,
                                               itemN, catN, Awt, Bmfb, W4fb, W1f, W2f,
                                               itemb, catb);
    attn_kernel<<<B / 4, 256, 0, stream>>>(cid, cg, cc, hg, hc,
                                           user_table, item_table, cat_table,
                                           ab1, aw2, Awt, Bmfb, W4fb, itemb, catb, cfrag);
    mlp_kernel<<<B / 16, 256, 0, stream>>>(cfrag, W1f, W2f,
                                           mb1, mb2, mw3, mb3, out);
}

// Round 9
// 202.407 us; speedup vs baseline: 1.0448x; 1.0448x over previous
//
#include <hip/hip_runtime.h>
#include <hip/hip_bf16.h>
#include <math.h>

#define LHIST 50

typedef __attribute__((ext_vector_type(8))) short bf16x8;
typedef __attribute__((ext_vector_type(4))) float f32x4;

__device__ __forceinline__ unsigned short f2bf(float f) {
    union { float f; unsigned u; } v; v.f = f;
    unsigned r = v.u + 0x7fff + ((v.u >> 16) & 1);   // RNE
    return (unsigned short)(r >> 16);
}
__device__ __forceinline__ float bf2f(unsigned short h) {
    union { unsigned u; float f; } v; v.u = ((unsigned)h) << 16;
    return v.f;
}
__device__ __forceinline__ unsigned packbf2(float lo, float hi) {
    return (unsigned)f2bf(lo) | ((unsigned)f2bf(hi) << 16);
}
__device__ __forceinline__ unsigned pk2(float lo, float hi) {   // v_cvt_pk_bf16_f32
    __hip_bfloat162 h = __float22bfloat162_rn(make_float2(lo, hi));
    return *(unsigned*)&h;
}
__device__ __forceinline__ float bflo(unsigned u){ union{unsigned v;float f;} x; x.v = u << 16; return x.f; }
__device__ __forceinline__ float bfhi(unsigned u){ union{unsigned v;float f;} x; x.v = u & 0xffff0000u; return x.f; }

// ws float offsets:
//  Awt    [80][64] fp32                   @ 0         (5120)
//  Bmfb   frag bf16 [nt5][ks2][lane][8]   @ 5120      (2560 f)
//  W4fb   frag bf16 [nt5][ks2][lane][8]   @ 7680      (2560 f)
//  W1f    frag bf16 [nt16][ks5][lane][8]  @ 10240     (20480 f)
//  W2f    frag bf16 [nt8][ks8][lane][8]   @ 30720     (16384 f)
//  itemb  bf16 [NI*32]                    @ 47104     (NI*16 f)
//  catb   bf16 [NC*32]                    @ 47104+NI*16
//  cfrag  bf16 [B/16][ks5][lane][8]       after catb  (combined, MFMA A-frag layout)

__global__ void prep_kernel(const float* __restrict__ aw1,
                            const float* __restrict__ mw1,
                            const float* __restrict__ mw2,
                            const float* __restrict__ item_table,
                            const float* __restrict__ cat_table,
                            int itemN, int catN,
                            float* __restrict__ Awt,
                            unsigned short* __restrict__ Bmfb,
                            unsigned short* __restrict__ W4fb,
                            unsigned short* __restrict__ W1f,
                            unsigned short* __restrict__ W2f,
                            unsigned short* __restrict__ itemb,
                            unsigned short* __restrict__ catb) {
    int i = blockIdx.x * 256 + threadIdx.x;
    int i8 = i * 8;
    if (i8 + 7 < itemN) {
        float4 a = *(const float4*)&item_table[i8];
        float4 b = *(const float4*)&item_table[i8 + 4];
        uint4 r;
        r.x = pk2(a.x, a.y); r.y = pk2(a.z, a.w);
        r.z = pk2(b.x, b.y); r.w = pk2(b.z, b.w);
        *(uint4*)&itemb[i8] = r;
    }
    if (i8 + 7 < catN) {
        float4 a = *(const float4*)&cat_table[i8];
        float4 b = *(const float4*)&cat_table[i8 + 4];
        uint4 r;
        r.x = pk2(a.x, a.y); r.y = pk2(a.z, a.w);
        r.z = pk2(b.x, b.y); r.w = pk2(b.z, b.w);
        *(uint4*)&catb[i8] = r;
    }
    if (i < 5120) {
        int j = i >> 6, k = i & 63;
        Awt[i] = aw1[k * 80 + j] + aw1[(128 + k) * 80 + j];     // (W1+W3)^T
        int kk = i / 80, n = i - kk * 80;
        int nt = n >> 4, colw = n & 15, ks = kk >> 5, r = kk & 31, qd = r >> 3, off = r & 7;
        int d = ((nt * 2 + ks) * 64 + qd * 16 + colw) * 8 + off;
        Bmfb[d] = f2bf(aw1[(64 + kk) * 80 + n] - aw1[(128 + kk) * 80 + n]);  // W2-W3
        W4fb[d] = f2bf(aw1[(192 + kk) * 80 + n]);
    }
    if (i < 40960) {
        int kk = i >> 8, n = i & 255;
        int nt = n >> 4, colw = n & 15, ks = kk >> 5, r = kk & 31, qd = r >> 3, off = r & 7;
        W1f[((nt * 5 + ks) * 64 + qd * 16 + colw) * 8 + off] = f2bf(mw1[i]);
    }
    if (i < 32768) {
        int kk = i >> 7, n = i & 127;
        int nt = n >> 4, colw = n & 15, ks = kk >> 5, r = kk & 31, qd = r >> 3, off = r & 7;
        W2f[((nt * 8 + ks) * 64 + qd * 16 + colw) * 8 + off] = f2bf(mw2[i]);
    }
}

// ---------- attention: 2 batches/block, K=64, B' shared-build, att from live frags ----------
__global__ void __launch_bounds__(256, 6) attn_kernel(
    const int* __restrict__ cid, const int* __restrict__ cg,
    const int* __restrict__ cc,  const int* __restrict__ hg,
    const int* __restrict__ hc,
    const float* __restrict__ user_table, const float* __restrict__ item_table,
    const float* __restrict__ cat_table,
    const float* __restrict__ ab1, const float* __restrict__ aw2,
    const float* __restrict__ Awt, const unsigned short* __restrict__ Bmfb,
    const unsigned short* __restrict__ W4fb,
    const unsigned short* __restrict__ itemb, const unsigned short* __restrict__ catb,
    unsigned short* __restrict__ cfrag)
{
    __shared__ __align__(16) unsigned short sh_Bq[2][5120];   // [b][nt5][ks2][lane][8]
    __shared__ __align__(16) float sh_q[2][64];
    __shared__ float sh_bias[2][80];
    __shared__ float sh_sc[2][64];
    __shared__ float sh_aw2[80];
    __shared__ __align__(16) float sh_att[2][2][64];

    const int t = threadIdx.x;
    const int b0 = blockIdx.x * 2;
    const int wv = t >> 6;
    const int lane = t & 63;
    const int quad = lane >> 4;
    const int col = lane & 15;
    const int bb = wv >> 1;      // batch of this wave
    const int hwv = wv & 1;      // half of l-range
    const int b = b0 + bb;

    // ---- P0: per-wave history indices + issue gathers immediately (no LDS dep) ----
    int il[2], ic[2];
    #pragma unroll
    for (int mi = 0; mi < 2; ++mi) {
        int l = hwv * 32 + mi * 16 + col;
        int lc = (l < LHIST) ? l : 0;
        il[mi] = hg[b * LHIST + lc];
        ic[mi] = hc[b * LHIST + lc];
    }
    uint4 vi[2], vc[2];
    #pragma unroll
    for (int mi = 0; mi < 2; ++mi) {
        vi[mi] = *(const uint4*)&itemb[(size_t)il[mi] * 32 + quad * 8];
        vc[mi] = *(const uint4*)&catb[(size_t)ic[mi] * 32 + quad * 8];
    }
    // q (fp32 tables) + aw2
    if (t < 128) {
        int qbi = t >> 6, k = t & 63;
        int bq = b0 + qbi;
        float v = (k < 32) ? item_table[(size_t)cg[bq] * 32 + k]
                           : cat_table[(size_t)cc[bq] * 32 + (k - 32)];
        sh_q[qbi][k] = v;
    }
    if (t < 80) sh_aw2[t] = aw2[t];
    __syncthreads();

    // ---- P1: B' = Bm + diag(q).W4 — load/unpack weights ONCE, reuse for both batches ----
    for (int slot = t; slot < 640; slot += 256) {
        int j = slot * 8;
        int lane8 = slot & 63, ks = (slot >> 6) & 1;
        int kk = ks * 32 + (lane8 >> 4) * 8;
        uint4 bm4 = *(const uint4*)&Bmfb[j];
        uint4 w44 = *(const uint4*)&W4fb[j];
        unsigned bw[4] = {bm4.x, bm4.y, bm4.z, bm4.w};
        unsigned ww[4] = {w44.x, w44.y, w44.z, w44.w};
        float bl[8], wl4[8];
        #pragma unroll
        for (int d = 0; d < 4; ++d) {
            bl[2 * d] = bflo(bw[d]);  bl[2 * d + 1] = bfhi(bw[d]);
            wl4[2 * d] = bflo(ww[d]); wl4[2 * d + 1] = bfhi(ww[d]);
        }
        #pragma unroll
        for (int bb2 = 0; bb2 < 2; ++bb2) {
            float4 qa = *(const float4*)&sh_q[bb2][kk];
            float4 qb = *(const float4*)&sh_q[bb2][kk + 4];
            float qv[8] = {qa.x, qa.y, qa.z, qa.w, qb.x, qb.y, qb.z, qb.w};
            uint4 res;
            unsigned* rp = (unsigned*)&res;
            #pragma unroll
            for (int d = 0; d < 4; ++d)
                rp[d] = pk2(bl[2 * d]     + qv[2 * d]     * wl4[2 * d],
                            bl[2 * d + 1] + qv[2 * d + 1] * wl4[2 * d + 1]);
            *(uint4*)&sh_Bq[bb2][j] = res;
        }
    }
    // bias[b][j] = ab1[j] + q.(W1+W3)[:,j]  (fp32 exact)
    if (t < 160) {
        int bi = t >= 80;
        int j = t - bi * 80;
        float acc = ab1[j];
        const float4* aw = (const float4*)&Awt[j * 64];
        #pragma unroll
        for (int k4 = 0; k4 < 16; ++k4) {
            float4 a = aw[k4];
            float4 q = *(const float4*)&sh_q[bi][k4 * 4];
            acc += a.x * q.x + a.y * q.y + a.z * q.z + a.w * q.w;
        }
        sh_bias[bi][j] = acc;
    }
    __syncthreads();

    // ---- P2: MFMA u = h[32 rows x K64] @ B'[64x80] per wave ----
    float bias_v[5], a2_v[5];
    #pragma unroll
    for (int nt = 0; nt < 5; ++nt) {
        bias_v[nt] = sh_bias[bb][nt * 16 + col];
        a2_v[nt]   = sh_aw2[nt * 16 + col];
    }
    f32x4 acc[2][5];
    #pragma unroll
    for (int mi = 0; mi < 2; ++mi)
        #pragma unroll
        for (int nt = 0; nt < 5; ++nt) acc[mi][nt] = (f32x4){0.f, 0.f, 0.f, 0.f};
    bf16x8 a0i = *(bf16x8*)&vi[0];
    bf16x8 a0c = *(bf16x8*)&vc[0];
    bf16x8 a1i = *(bf16x8*)&vi[1];
    bf16x8 a1c = *(bf16x8*)&vc[1];
    #pragma unroll
    for (int nt = 0; nt < 5; ++nt) {
        bf16x8 bfr0 = *(const bf16x8*)&sh_Bq[bb][((nt * 2 + 0) * 64 + lane) * 8];
        acc[0][nt] = __builtin_amdgcn_mfma_f32_16x16x32_bf16(a0i, bfr0, acc[0][nt], 0, 0, 0);
        acc[1][nt] = __builtin_amdgcn_mfma_f32_16x16x32_bf16(a1i, bfr0, acc[1][nt], 0, 0, 0);
        bf16x8 bfr1 = *(const bf16x8*)&sh_Bq[bb][((nt * 2 + 1) * 64 + lane) * 8];
        acc[0][nt] = __builtin_amdgcn_mfma_f32_16x16x32_bf16(a0c, bfr1, acc[0][nt], 0, 0, 0);
        acc[1][nt] = __builtin_amdgcn_mfma_f32_16x16x32_bf16(a1c, bfr1, acc[1][nt], 0, 0, 0);
    }
    // epilogue: scores = relu(u+bias).aw2, reduce over 16 col lanes
    #pragma unroll
    for (int mi = 0; mi < 2; ++mi) {
        int lbase = hwv * 32 + mi * 16 + quad * 4;
        #pragma unroll
        for (int i = 0; i < 4; ++i) {
            float pp = 0.f;
            #pragma unroll
            for (int nt = 0; nt < 5; ++nt) {
                float u = acc[mi][nt][i] + bias_v[nt];
                pp += fmaxf(u, 0.f) * a2_v[nt];
            }
            pp += __shfl_xor(pp, 1);
            pp += __shfl_xor(pp, 2);
            pp += __shfl_xor(pp, 4);
            pp += __shfl_xor(pp, 8);
            if (col == 0) sh_sc[bb][lbase + i] = pp;
        }
    }
    __syncthreads();

    // ---- softmax (wave-local, redundant across the 2 waves of each batch) ----
    float sc = -INFINITY;
    if (lane < LHIST) {
        sc = sh_sc[bb][lane];
        if (hg[b * LHIST + lane] == 0) sc = -1e9f;
    }
    float m = sc;
    #pragma unroll
    for (int off = 32; off > 0; off >>= 1) m = fmaxf(m, __shfl_xor(m, off));
    float e = (lane < LHIST) ? __expf(sc - m) : 0.f;
    float ssum = e;
    #pragma unroll
    for (int off = 32; off > 0; off >>= 1) ssum += __shfl_xor(ssum, off);
    float w = e / ssum;    // 0 for lane >= LHIST

    // ---- att from live h-frags: wl broadcast + per-lane partials + col-reduce ----
    {
        float wl[2];
        wl[0] = __shfl(w, hwv * 32 + col);
        wl[1] = __shfl(w, hwv * 32 + 16 + col);
        float at0[8], at1[8];
        #pragma unroll
        for (int j = 0; j < 8; ++j) { at0[j] = 0.f; at1[j] = 0.f; }
        #pragma unroll
        for (int mi = 0; mi < 2; ++mi) {
            union { uint4 u; unsigned short s[8]; } hi, hcv;
            hi.u = vi[mi]; hcv.u = vc[mi];
            #pragma unroll
            for (int j = 0; j < 8; ++j) {
                at0[j] += wl[mi] * bf2f(hi.s[j]);
                at1[j] += wl[mi] * bf2f(hcv.s[j]);
            }
        }
        #pragma unroll
        for (int off = 1; off < 16; off <<= 1)
            #pragma unroll
            for (int j = 0; j < 8; ++j) {
                at0[j] += __shfl_xor(at0[j], off);
                at1[j] += __shfl_xor(at1[j], off);
            }
        if (col == 0) {   // lanes quad*16: item d = quad*8+j, cat d = 32+quad*8+j
            *(float4*)&sh_att[bb][hwv][quad * 8]     = make_float4(at0[0], at0[1], at0[2], at0[3]);
            *(float4*)&sh_att[bb][hwv][quad * 8 + 4] = make_float4(at0[4], at0[5], at0[6], at0[7]);
            *(float4*)&sh_att[bb][hwv][32 + quad * 8]     = make_float4(at1[0], at1[1], at1[2], at1[3]);
            *(float4*)&sh_att[bb][hwv][32 + quad * 8 + 4] = make_float4(at1[4], at1[5], at1[6], at1[7]);
        }
    }
    __syncthreads();

    // ---- P5: waves 0,1 write combined in MFMA A-frag layout (bf16) ----
    if (wv < 2) {
        int bo = b0 + wv;
        int g = bo >> 4, colm = bo & 15;
        unsigned short* base = cfrag + (size_t)g * 2560;
        if (lane < 8) {                       // att chunks: k = 96 + lane*8
            float4 a0 = *(const float4*)&sh_att[wv][0][lane * 8];
            float4 a1 = *(const float4*)&sh_att[wv][1][lane * 8];
            float4 b0v = *(const float4*)&sh_att[wv][0][lane * 8 + 4];
            float4 b1v = *(const float4*)&sh_att[wv][1][lane * 8 + 4];
            int k0 = 96 + lane * 8;
            int ks = k0 >> 5, qd = (k0 >> 3) & 3;
            uint4 r;
            r.x = pk2(a0.x + a1.x, a0.y + a1.y); r.y = pk2(a0.z + a1.z, a0.w + a1.w);
            r.z = pk2(b0v.x + b1v.x, b0v.y + b1v.y); r.w = pk2(b0v.z + b1v.z, b0v.w + b1v.w);
            *(uint4*)(base + ((ks * 64) + qd * 16 + colm) * 8) = r;
        } else if (lane < 16) {               // q chunks: k = 32 + (lane-8)*8
            int cq = lane - 8;
            int k0 = 32 + cq * 8;
            int ks = k0 >> 5, qd = (k0 >> 3) & 3;
            float4 qa = *(const float4*)&sh_q[wv][cq * 8];
            float4 qb = *(const float4*)&sh_q[wv][cq * 8 + 4];
            uint4 r;
            r.x = pk2(qa.x, qa.y); r.y = pk2(qa.z, qa.w);
            r.z = pk2(qb.x, qb.y); r.w = pk2(qb.z, qb.w);
            *(uint4*)(base + ((ks * 64) + qd * 16 + colm) * 8) = r;
        } else if (lane < 20) {               // user chunks: k = (lane-16)*8
            int cu = lane - 16;
            int uidx = cid[bo];
            float4 ua = *(const float4*)&user_table[(size_t)uidx * 32 + cu * 8];
            float4 ub = *(const float4*)&user_table[(size_t)uidx * 32 + cu * 8 + 4];
            uint4 r;
            r.x = pk2(ua.x, ua.y); r.y = pk2(ua.z, ua.w);
            r.z = pk2(ub.x, ub.y); r.w = pk2(ub.z, ub.w);
            *(uint4*)(base + (cu * 16 + colm) * 8) = r;
        }
    }
}

// ---------- MLP: MFMA, 16 batches (1 m-tile) per 256-thread block ----------
__global__ void __launch_bounds__(256, 4) mlp_kernel(
    const unsigned short* __restrict__ cfrag,
    const unsigned short* __restrict__ W1f, const unsigned short* __restrict__ W2f,
    const float* __restrict__ mb1, const float* __restrict__ mb2,
    const float* __restrict__ mw3, const float* __restrict__ mb3,
    float* __restrict__ out)
{
    __shared__ __align__(16) unsigned short shA2[4096];   // [ks8][lane][8]
    __shared__ float sh_part[4][16];

    const int t = threadIdx.x;
    const int g = blockIdx.x;
    const int wv = t >> 6;
    const int lane = t & 63;
    const int quad = lane >> 4;
    const int col = lane & 15;
    const unsigned short* abase = cfrag + (size_t)g * 2560;

    f32x4 acc1[4];
    #pragma unroll
    for (int j = 0; j < 4; ++j) acc1[j] = (f32x4){0.f, 0.f, 0.f, 0.f};
    #pragma unroll
    for (int ks = 0; ks < 5; ++ks) {
        bf16x8 a = *(const bf16x8*)&abase[(ks * 64 + lane) * 8];
        #pragma unroll
        for (int j = 0; j < 4; ++j) {
            bf16x8 bw = *(const bf16x8*)&W1f[(((wv * 4 + j) * 5 + ks) * 64 + lane) * 8];
            acc1[j] = __builtin_amdgcn_mfma_f32_16x16x32_bf16(a, bw, acc1[j], 0, 0, 0);
        }
    }
    #pragma unroll
    for (int j = 0; j < 4; ++j) {
        int n = (wv * 4 + j) * 16 + col;
        float bj = mb1[n];
        int ks2 = n >> 5, qd2 = (n >> 3) & 3, off2 = n & 7;
        #pragma unroll
        for (int i = 0; i < 4; ++i) {
            float z = fmaxf(acc1[j][i] + bj, 0.f);
            shA2[(ks2 * 64 + qd2 * 16 + quad * 4 + i) * 8 + off2] = f2bf(z);
        }
    }
    __syncthreads();

    f32x4 acc2[2];
    #pragma unroll
    for (int jj = 0; jj < 2; ++jj) acc2[jj] = (f32x4){0.f, 0.f, 0.f, 0.f};
    #pragma unroll
    for (int ks = 0; ks < 8; ++ks) {
        bf16x8 a = *(const bf16x8*)&shA2[(ks * 64 + lane) * 8];
        #pragma unroll
        for (int jj = 0; jj < 2; ++jj) {
            bf16x8 bw = *(const bf16x8*)&W2f[(((wv * 2 + jj) * 8 + ks) * 64 + lane) * 8];
            acc2[jj] = __builtin_amdgcn_mfma_f32_16x16x32_bf16(a, bw, acc2[jj], 0, 0, 0);
        }
    }
    #pragma unroll
    for (int i = 0; i < 4; ++i) {
        float p = 0.f;
        #pragma unroll
        for (int jj = 0; jj < 2; ++jj) {
            int n = (wv * 2 + jj) * 16 + col;
            float z = fmaxf(acc2[jj][i] + mb2[n], 0.f);
            p += z * mw3[n];
        }
        p += __shfl_xor(p, 1);
        p += __shfl_xor(p, 2);
        p += __shfl_xor(p, 4);
        p += __shfl_xor(p, 8);
        if (col == 0) sh_part[wv][quad * 4 + i] = p;
    }
    __syncthreads();
    if (t < 16)
        out[g * 16 + t] = sh_part[0][t] + sh_part[1][t] + sh_part[2][t] + sh_part[3][t] + mb3[0];
}

extern "C" void kernel_launch(void* const* d_in, const int* in_sizes, int n_in,
                              void* d_out, int out_size, void* d_ws, size_t ws_size,
                              hipStream_t stream) {
    const int*   cid = (const int*)d_in[0];
    const int*   cg  = (const int*)d_in[1];
    const int*   cc  = (const int*)d_in[2];
    const int*   hg  = (const int*)d_in[3];
    const int*   hc  = (const int*)d_in[4];
    const float* user_table = (const float*)d_in[5];
    const float* item_table = (const float*)d_in[6];
    const float* cat_table  = (const float*)d_in[7];
    const float* aw1 = (const float*)d_in[8];
    const float* ab1 = (const float*)d_in[9];
    const float* aw2 = (const float*)d_in[10];
    const float* mw1 = (const float*)d_in[12];
    const float* mb1 = (const float*)d_in[13];
    const float* mw2 = (const float*)d_in[14];
    const float* mb2 = (const float*)d_in[15];
    const float* mw3 = (const float*)d_in[16];
    const float* mb3 = (const float*)d_in[17];
    float* out = (float*)d_out;

    const int B = in_sizes[0];                    // 16384
    const int itemN = in_sizes[6];                // NI*32
    const int catN  = in_sizes[7];                // NC*32
    float* ws = (float*)d_ws;
    float* Awt = ws;
    unsigned short* Bmfb = (unsigned short*)(ws + 5120);
    unsigned short* W4fb = (unsigned short*)(ws + 7680);
    unsigned short* W1f  = (unsigned short*)(ws + 10240);
    unsigned short* W2f  = (unsigned short*)(ws + 30720);
    unsigned short* itemb = (unsigned short*)(ws + 47104);
    unsigned short* catb  = itemb + itemN;
    unsigned short* cfrag = (unsigned short*)(ws + 47104 + (itemN + catN + 1) / 2);

    int n8 = (itemN + 7) / 8;
    int prep_grid = (n8 + 255) / 256;
    if (prep_grid < 160) prep_grid = 160;
    prep_kernel<<<prep_grid, 256, 0, stream>>>(aw1, mw1, mw2, item_table, cat_table,
                                               itemN, catN, Awt, Bmfb, W4fb, W1f, W2f,
                                               itemb, catb);
    attn_kernel<<<B / 2, 256, 0, stream>>>(cid, cg, cc, hg, hc,
                                           user_table, item_table, cat_table,
                                           ab1, aw2, Awt, Bmfb, W4fb, itemb, catb, cfrag);
    mlp_kernel<<<B / 16, 256, 0, stream>>>(cfrag, W1f, W2f,
                                           mb1, mb2, mw3, mb3, out);
}

// Round 10
// 189.400 us; speedup vs baseline: 1.1165x; 1.0687x over previous
//
#include <hip/hip_runtime.h>
#include <hip/hip_bf16.h>
#include <math.h>

#define LHIST 50

typedef __attribute__((ext_vector_type(8))) short bf16x8;
typedef __attribute__((ext_vector_type(4))) float f32x4;

__device__ __forceinline__ unsigned short f2bf(float f) {
    union { float f; unsigned u; } v; v.f = f;
    unsigned r = v.u + 0x7fff + ((v.u >> 16) & 1);   // RNE
    return (unsigned short)(r >> 16);
}
__device__ __forceinline__ float bf2f(unsigned short h) {
    union { unsigned u; float f; } v; v.u = ((unsigned)h) << 16;
    return v.f;
}
__device__ __forceinline__ unsigned pk2(float lo, float hi) {   // v_cvt_pk_bf16_f32
    __hip_bfloat162 h = __float22bfloat162_rn(make_float2(lo, hi));
    return *(unsigned*)&h;
}
__device__ __forceinline__ float bflo(unsigned u){ union{unsigned v;float f;} x; x.v = u << 16; return x.f; }
__device__ __forceinline__ float bfhi(unsigned u){ union{unsigned v;float f;} x; x.v = u & 0xffff0000u; return x.f; }

// ws float offsets:
//  Awt    [80][64] fp32                   @ 0         (5120)
//  Bmfb   frag bf16 [nt5][ks2][lane][8]   @ 5120      (2560 f)
//  W4fb   frag bf16 [nt5][ks2][lane][8]   @ 7680      (2560 f)
//  W1f    frag bf16 [nt16][ks5][lane][8]  @ 10240     (20480 f)
//  W2f    frag bf16 [nt8][ks8][lane][8]   @ 30720     (16384 f)
//  itemb  bf16 [NI*32]                    @ 47104     (NI*16 f)
//  catb   bf16 [NC*32]                    @ 47104+NI*16
//  combined [B][160] fp32                 after catb

__global__ void prep_kernel(const float* __restrict__ aw1,
                            const float* __restrict__ mw1,
                            const float* __restrict__ mw2,
                            const float* __restrict__ item_table,
                            const float* __restrict__ cat_table,
                            int itemN, int catN,
                            float* __restrict__ Awt,
                            unsigned short* __restrict__ Bmfb,
                            unsigned short* __restrict__ W4fb,
                            unsigned short* __restrict__ W1f,
                            unsigned short* __restrict__ W2f,
                            unsigned short* __restrict__ itemb,
                            unsigned short* __restrict__ catb) {
    int i = blockIdx.x * 256 + threadIdx.x;
    int i8 = i * 8;
    if (i8 + 7 < itemN) {
        float4 a = *(const float4*)&item_table[i8];
        float4 b = *(const float4*)&item_table[i8 + 4];
        uint4 r;
        r.x = pk2(a.x, a.y); r.y = pk2(a.z, a.w);
        r.z = pk2(b.x, b.y); r.w = pk2(b.z, b.w);
        *(uint4*)&itemb[i8] = r;
    }
    if (i8 + 7 < catN) {
        float4 a = *(const float4*)&cat_table[i8];
        float4 b = *(const float4*)&cat_table[i8 + 4];
        uint4 r;
        r.x = pk2(a.x, a.y); r.y = pk2(a.z, a.w);
        r.z = pk2(b.x, b.y); r.w = pk2(b.z, b.w);
        *(uint4*)&catb[i8] = r;
    }
    if (i < 5120) {
        int j = i >> 6, k = i & 63;
        Awt[i] = aw1[k * 80 + j] + aw1[(128 + k) * 80 + j];     // (W1+W3)^T
        int kk = i / 80, n = i - kk * 80;
        int nt = n >> 4, colw = n & 15, ks = kk >> 5, r = kk & 31, qd = r >> 3, off = r & 7;
        int d = ((nt * 2 + ks) * 64 + qd * 16 + colw) * 8 + off;
        Bmfb[d] = f2bf(aw1[(64 + kk) * 80 + n] - aw1[(128 + kk) * 80 + n]);  // W2-W3
        W4fb[d] = f2bf(aw1[(192 + kk) * 80 + n]);
    }
    if (i < 40960) {
        int kk = i >> 8, n = i & 255;
        int nt = n >> 4, colw = n & 15, ks = kk >> 5, r = kk & 31, qd = r >> 3, off = r & 7;
        W1f[((nt * 5 + ks) * 64 + qd * 16 + colw) * 8 + off] = f2bf(mw1[i]);
    }
    if (i < 32768) {
        int kk = i >> 7, n = i & 127;
        int nt = n >> 4, colw = n & 15, ks = kk >> 5, r = kk & 31, qd = r >> 3, off = r & 7;
        W2f[((nt * 8 + ks) * 64 + qd * 16 + colw) * 8 + off] = f2bf(mw2[i]);
    }
}

// ---------- attention: 2 batches/block, transposed MFMA (j on rows, l on cols) ----------
__global__ void __launch_bounds__(256, 6) attn_kernel(
    const int* __restrict__ cid, const int* __restrict__ cg,
    const int* __restrict__ cc,  const int* __restrict__ hg,
    const int* __restrict__ hc,
    const float* __restrict__ user_table, const float* __restrict__ item_table,
    const float* __restrict__ cat_table,
    const float* __restrict__ ab1, const float* __restrict__ aw2,
    const float* __restrict__ Awt, const unsigned short* __restrict__ Bmfb,
    const unsigned short* __restrict__ W4fb,
    const unsigned short* __restrict__ itemb, const unsigned short* __restrict__ catb,
    float* __restrict__ combined)
{
    __shared__ __align__(16) unsigned short sh_Bq[2][5120];   // [b][nt5][ks2][lane][8]; reused as att scratch
    __shared__ __align__(16) float sh_q[2][64];
    __shared__ float sh_bias[2][80];
    __shared__ float sh_sc[2][64];
    __shared__ float sh_aw2[80];
    __shared__ float sh_att[4][64];

    const int t = threadIdx.x;
    const int b0 = blockIdx.x * 2;
    const int wv = t >> 6;
    const int lane = t & 63;
    const int quad = lane >> 4;
    const int col = lane & 15;
    const int bb = wv >> 1;      // batch of this wave
    const int hwv = wv & 1;      // half of l-range
    const int b = b0 + bb;

    // ---- P0: per-wave history indices + issue gathers immediately ----
    int il[2], ic[2];
    #pragma unroll
    for (int mi = 0; mi < 2; ++mi) {
        int l = hwv * 32 + mi * 16 + col;
        int lc = (l < LHIST) ? l : 0;
        il[mi] = hg[b * LHIST + lc];
        ic[mi] = hc[b * LHIST + lc];
    }
    uint4 vi[2], vc[2];
    #pragma unroll
    for (int mi = 0; mi < 2; ++mi) {
        vi[mi] = *(const uint4*)&itemb[(size_t)il[mi] * 32 + quad * 8];
        vc[mi] = *(const uint4*)&catb[(size_t)ic[mi] * 32 + quad * 8];
    }
    if (t < 128) {
        int qbi = t >> 6, k = t & 63;
        int bq = b0 + qbi;
        float v = (k < 32) ? item_table[(size_t)cg[bq] * 32 + k]
                           : cat_table[(size_t)cc[bq] * 32 + (k - 32)];
        sh_q[qbi][k] = v;
    }
    if (t < 80) sh_aw2[t] = aw2[t];
    __syncthreads();

    // ---- P1: B' = Bm + diag(q).W4 — load weights once, emit for both batches ----
    for (int slot = t; slot < 640; slot += 256) {
        int j = slot * 8;
        int lane8 = slot & 63, ks = (slot >> 6) & 1;
        int kk = ks * 32 + (lane8 >> 4) * 8;
        uint4 bm4 = *(const uint4*)&Bmfb[j];
        uint4 w44 = *(const uint4*)&W4fb[j];
        unsigned bw[4] = {bm4.x, bm4.y, bm4.z, bm4.w};
        unsigned ww[4] = {w44.x, w44.y, w44.z, w44.w};
        float bl[8], wl4[8];
        #pragma unroll
        for (int d = 0; d < 4; ++d) {
            bl[2 * d] = bflo(bw[d]);  bl[2 * d + 1] = bfhi(bw[d]);
            wl4[2 * d] = bflo(ww[d]); wl4[2 * d + 1] = bfhi(ww[d]);
        }
        #pragma unroll
        for (int bb2 = 0; bb2 < 2; ++bb2) {
            float4 qa = *(const float4*)&sh_q[bb2][kk];
            float4 qb = *(const float4*)&sh_q[bb2][kk + 4];
            float qv[8] = {qa.x, qa.y, qa.z, qa.w, qb.x, qb.y, qb.z, qb.w};
            uint4 res;
            unsigned* rp = (unsigned*)&res;
            #pragma unroll
            for (int d = 0; d < 4; ++d)
                rp[d] = pk2(bl[2 * d]     + qv[2 * d]     * wl4[2 * d],
                            bl[2 * d + 1] + qv[2 * d + 1] * wl4[2 * d + 1]);
            *(uint4*)&sh_Bq[bb2][j] = res;
        }
    }
    // bias[b][j] = ab1[j] + q.(W1+W3)[:,j]  (fp32 exact)
    if (t < 160) {
        int bi = t >= 80;
        int j = t - bi * 80;
        float acc = ab1[j];
        const float4* aw = (const float4*)&Awt[j * 64];
        #pragma unroll
        for (int k4 = 0; k4 < 16; ++k4) {
            float4 a = aw[k4];
            float4 q = *(const float4*)&sh_q[bi][k4 * 4];
            acc += a.x * q.x + a.y * q.y + a.z * q.z + a.w * q.w;
        }
        sh_bias[bi][j] = acc;
    }
    __syncthreads();

    // ---- preload per-lane bias/aw2 rows (j = jt*16 + quad*4 + i) ----
    float4 a2v[5], bv[5];
    #pragma unroll
    for (int jt = 0; jt < 5; ++jt) {
        a2v[jt] = *(const float4*)&sh_aw2[jt * 16 + quad * 4];
        bv[jt]  = *(const float4*)&sh_bias[bb][jt * 16 + quad * 4];
    }

    // ---- P2: transposed MFMA  D[j][l] = sum_d B'[d][j] * h[l][d] ----
    // A-operand = B' frags (sh_Bq), B-operand = h frags (vi/vc in registers).
    bf16x8 hi0 = *(bf16x8*)&vi[0];
    bf16x8 hc0 = *(bf16x8*)&vc[0];
    bf16x8 hi1 = *(bf16x8*)&vi[1];
    bf16x8 hc1 = *(bf16x8*)&vc[1];
    float px = 0.f, py = 0.f;    // score partials for l-tiles 0,1 (l = hwv*32 + lt*16 + col)
    #pragma unroll
    for (int jt = 0; jt < 5; ++jt) {
        f32x4 a0 = (f32x4){0.f, 0.f, 0.f, 0.f};
        f32x4 a1 = (f32x4){0.f, 0.f, 0.f, 0.f};
        bf16x8 A0 = *(const bf16x8*)&sh_Bq[bb][((jt * 2 + 0) * 64 + lane) * 8];
        bf16x8 A1 = *(const bf16x8*)&sh_Bq[bb][((jt * 2 + 1) * 64 + lane) * 8];
        a0 = __builtin_amdgcn_mfma_f32_16x16x32_bf16(A0, hi0, a0, 0, 0, 0);
        a0 = __builtin_amdgcn_mfma_f32_16x16x32_bf16(A1, hc0, a0, 0, 0, 0);
        a1 = __builtin_amdgcn_mfma_f32_16x16x32_bf16(A0, hi1, a1, 0, 0, 0);
        a1 = __builtin_amdgcn_mfma_f32_16x16x32_bf16(A1, hc1, a1, 0, 0, 0);
        const float* bp = (const float*)&bv[jt];
        const float* ap = (const float*)&a2v[jt];
        #pragma unroll
        for (int i = 0; i < 4; ++i) {
            px += fmaxf(a0[i] + bp[i], 0.f) * ap[i];
            py += fmaxf(a1[i] + bp[i], 0.f) * ap[i];
        }
    }
    // reduce over the 4 quad-lanes (j coverage); only 2 shfl stages each
    px += __shfl_xor(px, 16); px += __shfl_xor(px, 32);
    py += __shfl_xor(py, 16); py += __shfl_xor(py, 32);
    if (quad == 0) {
        sh_sc[bb][hwv * 32 + col] = px;
        sh_sc[bb][hwv * 32 + 16 + col] = py;
    }
    __syncthreads();

    // ---- softmax (wave-local) ----
    float sc = -INFINITY;
    if (lane < LHIST) {
        sc = sh_sc[bb][lane];
        if (hg[b * LHIST + lane] == 0) sc = -1e9f;
    }
    float m = sc;
    #pragma unroll
    for (int off = 32; off > 0; off >>= 1) m = fmaxf(m, __shfl_xor(m, off));
    float e = (lane < LHIST) ? __expf(sc - m) : 0.f;
    float ssum = e;
    #pragma unroll
    for (int off = 32; off > 0; off >>= 1) ssum += __shfl_xor(ssum, off);
    float w = e / ssum;    // 0 for lane >= LHIST

    // ---- att: per-lane partials, then LDS transpose-reduce (reuse sh_Bq, dead now) ----
    {
        float wl0 = __shfl(w, hwv * 32 + col);
        float wl1 = __shfl(w, hwv * 32 + 16 + col);
        union { uint4 u; unsigned short s[8]; } i0, i1, c0u, c1u;
        i0.u = vi[0]; i1.u = vi[1]; c0u.u = vc[0]; c1u.u = vc[1];
        float ati[8], atc[8];
        #pragma unroll
        for (int j = 0; j < 8; ++j) {
            ati[j] = wl0 * bf2f(i0.s[j]) + wl1 * bf2f(i1.s[j]);
            atc[j] = wl0 * bf2f(c0u.s[j]) + wl1 * bf2f(c1u.s[j]);
        }
        float* red = (float*)sh_Bq;                    // 5120 floats avail; need 4*1056
        float* myrow = red + wv * 1056 + col * 66;
        #pragma unroll
        for (int j2 = 0; j2 < 4; ++j2) {
            *(float2*)&myrow[quad * 8 + j2 * 2]      = make_float2(ati[2 * j2], ati[2 * j2 + 1]);
            *(float2*)&myrow[33 + quad * 8 + j2 * 2] = make_float2(atc[2 * j2], atc[2 * j2 + 1]);
        }
        int colIdx = (lane < 32) ? lane : 33 + (lane - 32);
        float s = 0.f;
        #pragma unroll
        for (int c = 0; c < 16; ++c) s += red[wv * 1056 + c * 66 + colIdx];
        sh_att[wv][lane] = s;                          // d = lane (0..31 item, 32..63 cat)
    }
    __syncthreads();

    // ---- write combined (coalesced fp32, R5-style) ----
    if (wv < 2) {
        int bo = b0 + wv;
        float* crow = combined + (size_t)bo * 160;
        crow[32 + lane] = sh_q[wv][lane];
        crow[96 + lane] = sh_att[2 * wv][lane] + sh_att[2 * wv + 1][lane];
        if (lane < 32) crow[lane] = user_table[(size_t)cid[bo] * 32 + lane];
    }
}

// ---------- MLP: MFMA, 32 batch rows per 256-thread block ----------
__global__ void __launch_bounds__(256, 4) mlp_kernel(
    const float* __restrict__ combined,
    const unsigned short* __restrict__ W1f, const unsigned short* __restrict__ W2f,
    const float* __restrict__ mb1, const float* __restrict__ mb2,
    const float* __restrict__ mw3, const float* __restrict__ mb3,
    float* __restrict__ out)
{
    __shared__ __align__(16) unsigned short shA1[5120];   // [mt2][ks5][lane][8]
    __shared__ __align__(16) unsigned short shA2[8192];   // [mt2][ks8][lane][8]
    __shared__ float sh_part[4][32];

    const int t = threadIdx.x;
    const int b0 = blockIdx.x * 32;
    const int wv = t >> 6;
    const int lane = t & 63;
    const int quad = lane >> 4;
    const int col = lane & 15;

    // pack A1 = combined bf16 frags
    for (int i = t; i < 1280; i += 256) {
        int m = i / 40;
        int s = i - m * 40;
        int k0 = s * 4;
        float4 v = *(const float4*)&combined[(size_t)(b0 + m) * 160 + k0];
        int mt = m >> 4, colm = m & 15;
        int ks = k0 >> 5, qd = (k0 >> 3) & 3, off = k0 & 7;
        ushort4 r; r.x = f2bf(v.x); r.y = f2bf(v.y); r.z = f2bf(v.z); r.w = f2bf(v.w);
        *(ushort4*)&shA1[((mt * 5 + ks) * 64 + qd * 16 + colm) * 8 + off] = r;
    }
    __syncthreads();

    f32x4 acc1[2][4];
    #pragma unroll
    for (int mt = 0; mt < 2; ++mt)
        #pragma unroll
        for (int j = 0; j < 4; ++j) acc1[mt][j] = (f32x4){0.f, 0.f, 0.f, 0.f};
    #pragma unroll
    for (int ks = 0; ks < 5; ++ks) {
        bf16x8 a0 = *(const bf16x8*)&shA1[(ks * 64 + lane) * 8];
        bf16x8 a1 = *(const bf16x8*)&shA1[((5 + ks) * 64 + lane) * 8];
        #pragma unroll
        for (int j = 0; j < 4; ++j) {
            int ntg = wv * 4 + j;
            bf16x8 bw = *(const bf16x8*)&W1f[((ntg * 5 + ks) * 64 + lane) * 8];
            acc1[0][j] = __builtin_amdgcn_mfma_f32_16x16x32_bf16(a0, bw, acc1[0][j], 0, 0, 0);
            acc1[1][j] = __builtin_amdgcn_mfma_f32_16x16x32_bf16(a1, bw, acc1[1][j], 0, 0, 0);
        }
    }
    #pragma unroll
    for (int j = 0; j < 4; ++j) {
        int n = (wv * 4 + j) * 16 + col;
        float bj = mb1[n];
        int ks2 = n >> 5, qd2 = (n >> 3) & 3, off2 = n & 7;
        #pragma unroll
        for (int mt = 0; mt < 2; ++mt)
            #pragma unroll
            for (int i = 0; i < 4; ++i) {
                float z = fmaxf(acc1[mt][j][i] + bj, 0.f);
                shA2[((mt * 8 + ks2) * 64 + qd2 * 16 + quad * 4 + i) * 8 + off2] = f2bf(z);
            }
    }
    __syncthreads();

    f32x4 acc2[2][2];
    #pragma unroll
    for (int mt = 0; mt < 2; ++mt)
        #pragma unroll
        for (int jj = 0; jj < 2; ++jj) acc2[mt][jj] = (f32x4){0.f, 0.f, 0.f, 0.f};
    #pragma unroll
    for (int ks = 0; ks < 8; ++ks) {
        bf16x8 a0 = *(const bf16x8*)&shA2[(ks * 64 + lane) * 8];
        bf16x8 a1 = *(const bf16x8*)&shA2[((8 + ks) * 64 + lane) * 8];
        #pragma unroll
        for (int jj = 0; jj < 2; ++jj) {
            int ntg = wv * 2 + jj;
            bf16x8 bw = *(const bf16x8*)&W2f[((ntg * 8 + ks) * 64 + lane) * 8];
            acc2[0][jj] = __builtin_amdgcn_mfma_f32_16x16x32_bf16(a0, bw, acc2[0][jj], 0, 0, 0);
            acc2[1][jj] = __builtin_amdgcn_mfma_f32_16x16x32_bf16(a1, bw, acc2[1][jj], 0, 0, 0);
        }
    }
    #pragma unroll
    for (int mt = 0; mt < 2; ++mt) {
        #pragma unroll
        for (int i = 0; i < 4; ++i) {
            float p = 0.f;
            #pragma unroll
            for (int jj = 0; jj < 2; ++jj) {
                int n = (wv * 2 + jj) * 16 + col;
                float z = fmaxf(acc2[mt][jj][i] + mb2[n], 0.f);
                p += z * mw3[n];
            }
            p += __shfl_xor(p, 1);
            p += __shfl_xor(p, 2);
            p += __shfl_xor(p, 4);
            p += __shfl_xor(p, 8);
            if (col == 0) sh_part[wv][mt * 16 + quad * 4 + i] = p;
        }
    }
    __syncthreads();
    if (t < 32)
        out[b0 + t] = sh_part[0][t] + sh_part[1][t] + sh_part[2][t] + sh_part[3][t] + mb3[0];
}

extern "C" void kernel_launch(void* const* d_in, const int* in_sizes, int n_in,
                              void* d_out, int out_size, void* d_ws, size_t ws_size,
                              hipStream_t stream) {
    const int*   cid = (const int*)d_in[0];
    const int*   cg  = (const int*)d_in[1];
    const int*   cc  = (const int*)d_in[2];
    const int*   hg  = (const int*)d_in[3];
    const int*   hc  = (const int*)d_in[4];
    const float* user_table = (const float*)d_in[5];
    const float* item_table = (const float*)d_in[6];
    const float* cat_table  = (const float*)d_in[7];
    const float* aw1 = (const float*)d_in[8];
    const float* ab1 = (const float*)d_in[9];
    const float* aw2 = (const float*)d_in[10];
    const float* mw1 = (const float*)d_in[12];
    const float* mb1 = (const float*)d_in[13];
    const float* mw2 = (const float*)d_in[14];
    const float* mb2 = (const float*)d_in[15];
    const float* mw3 = (const float*)d_in[16];
    const float* mb3 = (const float*)d_in[17];
    float* out = (float*)d_out;

    const int B = in_sizes[0];                    // 16384
    const int itemN = in_sizes[6];                // NI*32
    const int catN  = in_sizes[7];                // NC*32
    float* ws = (float*)d_ws;
    float* Awt = ws;
    unsigned short* Bmfb = (unsigned short*)(ws + 5120);
    unsigned short* W4fb = (unsigned short*)(ws + 7680);
    unsigned short* W1f  = (unsigned short*)(ws + 10240);
    unsigned short* W2f  = (unsigned short*)(ws + 30720);
    unsigned short* itemb = (unsigned short*)(ws + 47104);
    unsigned short* catb  = itemb + itemN;
    float* combined = ws + 47104 + (itemN + catN + 1) / 2;

    int n8 = (itemN + 7) / 8;
    int prep_grid = (n8 + 255) / 256;
    if (prep_grid < 160) prep_grid = 160;
    prep_kernel<<<prep_grid, 256, 0, stream>>>(aw1, mw1, mw2, item_table, cat_table,
                                               itemN, catN, Awt, Bmfb, W4fb, W1f, W2f,
                                               itemb, catb);
    attn_kernel<<<B / 2, 256, 0, stream>>>(cid, cg, cc, hg, hc,
                                           user_table, item_table, cat_table,
                                           ab1, aw2, Awt, Bmfb, W4fb, itemb, catb, combined);
    mlp_kernel<<<B / 32, 256, 0, stream>>>(combined, W1f, W2f,
                                           mb1, mb2, mw3, mb3, out);
}